// Round 3
// baseline (2751.614 us; speedup 1.0000x reference)
//
#include <hip/hip_runtime.h>
#include <hip/hip_bf16.h>

// ---------------------------------------------------------------------------
// MemoryEfficientFlashAttention: B=2 S=2048 HID=2048 H=16 HKV=8 D=128 CHUNK=512
// R3: k_attn rebuilt again — paired q-tiles (j, 31-j) per block for perfect
//     load balance, shared K/V staging + shared frag reads for both streams,
//     double-buffered global_load_lds (1 barrier/tile), MFMA ones-column row
//     sums, single u-accumulator, ballot-skipped rescale.
// ---------------------------------------------------------------------------

typedef __attribute__((ext_vector_type(8))) short s8v;   // 8 bf16 (4 VGPR) MFMA frag
typedef __attribute__((ext_vector_type(4))) float f4v;   // 4 fp32 acc frag

#define MFMA16(a, b, c) __builtin_amdgcn_mfma_f32_16x16x32_bf16((a), (b), (c), 0, 0, 0)

typedef unsigned short u16;
typedef const __attribute__((address_space(1))) unsigned int* gas_p;
typedef __attribute__((address_space(3))) unsigned int* las_p;

__device__ __forceinline__ void gl_lds16(const void* g, void* l) {
    __builtin_amdgcn_global_load_lds((gas_p)g, (las_p)l, 16, 0, 0);
}

__device__ __forceinline__ u16 f2b(float f) {
    __hip_bfloat16 h = __float2bfloat16(f);
    return *reinterpret_cast<u16*>(&h);
}
__device__ __forceinline__ float b2f(u16 u) {
    __hip_bfloat16 h;
    *reinterpret_cast<u16*>(&h) = u;
    return __bfloat162float(h);
}

// ---------------- cast hidden_states fp32 -> bf16 ---------------------------
__global__ __launch_bounds__(256) void k_cast_hs(const float* __restrict__ src,
                                                 u16* __restrict__ dst) {
    int i = blockIdx.x * 256 + threadIdx.x;
    float4 v = reinterpret_cast<const float4*>(src)[i];
    alignas(8) u16 t[4] = {f2b(v.x), f2b(v.y), f2b(v.z), f2b(v.w)};
    reinterpret_cast<uint2*>(dst)[i] = *reinterpret_cast<uint2*>(t);
}

// ------------- transpose+cast weights: W[K][N] fp32 -> Wt[N][K] bf16 --------
__global__ __launch_bounds__(256) void k_transpose_w(
    const float* __restrict__ Wq, const float* __restrict__ Wk,
    const float* __restrict__ Wv, const float* __restrict__ Wo,
    u16* __restrict__ wt_all, u16* __restrict__ wo_t) {
    int id = blockIdx.x;
    const float* W; u16* dst; int N, nbase;
    if (id < 4096)      { W = Wq; dst = wt_all; N = 2048; nbase = 0; }
    else if (id < 6144) { W = Wk; dst = wt_all; N = 1024; nbase = 2048; id -= 4096; }
    else if (id < 8192) { W = Wv; dst = wt_all; N = 1024; nbase = 3072; id -= 6144; }
    else                { W = Wo; dst = wo_t;  N = 2048; nbase = 0;    id -= 8192; }
    int tiles_n = N >> 5;
    int k0 = (id / tiles_n) << 5, n0 = (id % tiles_n) << 5;
    __shared__ float t[32][33];
    int tid = threadIdx.x, c = tid & 31, rr = tid >> 5;
#pragma unroll
    for (int i = 0; i < 4; i++) {
        int kk = rr + i * 8;
        t[kk][c] = W[(size_t)(k0 + kk) * N + n0 + c];
    }
    __syncthreads();
#pragma unroll
    for (int i = 0; i < 4; i++) {
        int n = rr + i * 8;
        dst[(size_t)(nbase + n0 + n) * 2048 + k0 + c] = f2b(t[c][n]);
    }
}

// ---------------- concat biases bq|bk|bv -> fp32[4096] ----------------------
__global__ __launch_bounds__(256) void k_bias(const float* __restrict__ bq,
                                              const float* __restrict__ bk,
                                              const float* __restrict__ bv,
                                              float* __restrict__ dst) {
    int i = blockIdx.x * 256 + threadIdx.x;
    float v = (i < 2048) ? bq[i] : (i < 3072) ? bk[i - 2048] : bv[i - 3072];
    dst[i] = v;
}

// ---------------- bf16 MFMA GEMM: C[M][N] = A[M][K] * Bt[N][K]^T + bias -----
__global__ __launch_bounds__(256) void k_gemm(
    const u16* __restrict__ A, const u16* __restrict__ Bt,
    const float* __restrict__ bias, void* __restrict__ out,
    int M, int N, int K, int out_f32) {
    __shared__ alignas(16) u16 As[128][32];
    __shared__ alignas(16) u16 Bs[128][32];
    int tid = threadIdx.x;
    int wave = tid >> 6, lane = tid & 63, quad = lane >> 4, l16 = lane & 15;
    int m0 = blockIdx.y << 7, n0 = blockIdx.x << 7;
    int wm = (wave >> 1) << 6, wn = (wave & 1) << 6;
    f4v zero = {0.f, 0.f, 0.f, 0.f};
    f4v acc[4][4];
#pragma unroll
    for (int a = 0; a < 4; a++)
#pragma unroll
        for (int b = 0; b < 4; b++) acc[a][b] = zero;
    int r0 = tid >> 2, cb = (tid & 3) << 3;
    const u16* gA = A + (size_t)(m0 + r0) * K + cb;
    const u16* gB = Bt + (size_t)(n0 + r0) * K + cb;
    for (int k0 = 0; k0 < K; k0 += 32) {
        __syncthreads();
#pragma unroll
        for (int i = 0; i < 2; i++) {
            gl_lds16(gA + (size_t)(i << 6) * K + k0, (char*)As + (i << 12) + tid * 16);
            gl_lds16(gB + (size_t)(i << 6) * K + k0, (char*)Bs + (i << 12) + tid * 16);
        }
        __syncthreads();
        s8v af[4], bf_[4];
#pragma unroll
        for (int mi = 0; mi < 4; mi++)
            af[mi] = *reinterpret_cast<const s8v*>(&As[wm + mi * 16 + l16][quad << 3]);
#pragma unroll
        for (int ni = 0; ni < 4; ni++)
            bf_[ni] = *reinterpret_cast<const s8v*>(&Bs[wn + ni * 16 + l16][quad << 3]);
#pragma unroll
        for (int mi = 0; mi < 4; mi++)
#pragma unroll
            for (int ni = 0; ni < 4; ni++)
                acc[mi][ni] = MFMA16(af[mi], bf_[ni], acc[mi][ni]);
    }
#pragma unroll
    for (int mi = 0; mi < 4; mi++) {
#pragma unroll
        for (int ni = 0; ni < 4; ni++) {
            int n = n0 + wn + ni * 16 + l16;
            float bsv = bias[n];
#pragma unroll
            for (int r = 0; r < 4; r++) {
                int m = m0 + wm + mi * 16 + (quad << 2) + r;
                float v = acc[mi][ni][r] + bsv;
                if (out_f32)
                    reinterpret_cast<float*>(out)[(size_t)m * N + n] = v;
                else
                    reinterpret_cast<u16*>(out)[(size_t)m * N + n] = f2b(v);
            }
        }
    }
}

// ---------------- RoPE on Q and K, reshape to [B,H,S,D] ---------------------
__global__ __launch_bounds__(256) void k_rope(const u16* __restrict__ qkv,
                                              u16* __restrict__ qr,
                                              u16* __restrict__ kr) {
    int row = blockIdx.x;
    int b = row >> 11, s = row & 2047;
    const u16* src = qkv + (size_t)row * 4096;
    __shared__ float lcs[64], lsn[64];
    int tid = threadIdx.x;
    if (tid < 64) {
        float fr = (float)s * exp2f((float)tid * -0.31143075889569023f);
        lcs[tid] = cosf(fr);
        lsn[tid] = sinf(fr);
    }
    __syncthreads();
    for (int u = tid; u < 1536; u += 256) {
        int hh, i;
        const u16* sp;
        u16* dp;
        if (u < 1024) {
            hh = u >> 6; i = u & 63;
            sp = src + hh * 128;
            dp = qr + ((size_t)(b * 16 + hh) * 2048 + s) * 128;
        } else {
            int u2 = u - 1024;
            hh = u2 >> 6; i = u2 & 63;
            sp = src + 2048 + hh * 128;
            dp = kr + ((size_t)(b * 8 + hh) * 2048 + s) * 128;
        }
        float x1 = b2f(sp[i]);
        float x2 = b2f(sp[i + 64]);
        float cs = lcs[i], sn = lsn[i];
        dp[i]      = f2b(x1 * cs - x2 * sn);
        dp[i + 64] = f2b(x2 * cs + x1 * sn);
    }
}

// ---------------- V: reshape + transpose -> vt[B,HKV,D,S] bf16 --------------
__global__ __launch_bounds__(256) void k_vtrans(const u16* __restrict__ qkv,
                                                u16* __restrict__ vt) {
    int bkv = blockIdx.z, b = bkv >> 3, kv = bkv & 7;
    int s0 = blockIdx.x << 6, d0 = blockIdx.y << 5;
    __shared__ alignas(16) u16 t[32][72];
    int tid = threadIdx.x, c = tid & 31, rr = tid >> 5;
#pragma unroll
    for (int i = 0; i < 8; i++) {
        int s = s0 + rr + i * 8;
        t[c][rr + i * 8] = qkv[(size_t)(b * 2048 + s) * 4096 + 3072 + kv * 128 + d0 + c];
    }
    __syncthreads();
    int dd = tid >> 3, sc8 = (tid & 7) << 3;
    *reinterpret_cast<uint4*>(&vt[((size_t)(b * 8 + kv) * 128 + d0 + dd) * 2048 + s0 + sc8]) =
        *reinterpret_cast<const uint4*>(&t[dd][sc8]);
}

// ---------------- attention (reference recurrence, chunk-exact) -------------
// Block = 4 waves = 256 thr, owns q-tile pair {H = 31-j, L = j} of one (b,h):
// constant 33 tile-units/block. Tile t stages K/V once (double-buffered
// global_load_lds, 1 barrier/tile); both streams share kf/vf LDS frag reads.
// u-accumulator: u = o_prev*prod(alpha) + sum(rescaled PV); at chunk close
// u /= (exp(m_prev-mc)+sums) — identical to the reference scan step.
// Row sums via MFMA against a ones fragment (no shuffle reduction).
__global__ __launch_bounds__(256, 2) void k_attn(const u16* __restrict__ qr,
                                                 const u16* __restrict__ kr,
                                                 const u16* __restrict__ vt,
                                                 u16* __restrict__ attnb) {
    const float scale = 0.08838834764831845f;   // 1/sqrt(128)
    const float NINF = -__builtin_inff();
    __shared__ alignas(16) u16 Ks[2][64 * 128];   // [key][dim], granule-swizzled
    __shared__ alignas(16) u16 Vs[2][128 * 64];   // [d][key],  granule-swizzled
    __shared__ alignas(16) u16 Pb[2][4][16][40];  // [stream][wave][row][32key+8pad]

    int tid = threadIdx.x;
    int wv = tid >> 6, lane = tid & 63, quad = lane >> 4, l16 = lane & 15;
    int j = blockIdx.x;                          // 0..15
    int h = blockIdx.y, b = blockIdx.z, kvh = h >> 1;
    int qtH = 31 - j, qtL = j;
    int diagH = qtH, diagL = qtL;                // diagonal 64-key tile index
    int nt = 32 - j;                             // tiles processed (heavy range)
    const u16* QpH = qr + ((size_t)(b * 16 + h) * 2048 + qtH * 64 + wv * 16) * 128;
    const u16* QpL = qr + ((size_t)(b * 16 + h) * 2048 + qtL * 64 + wv * 16) * 128;
    const u16* Kp = kr + ((size_t)(b * 8 + kvh) * 2048) * 128;
    const u16* Vp = vt + ((size_t)(b * 8 + kvh) * 128) * 2048;

    s8v qfH[4], qfL[4];
#pragma unroll
    for (int sl = 0; sl < 4; sl++) {
        qfH[sl] = *reinterpret_cast<const s8v*>(&QpH[l16 * 128 + sl * 32 + (quad << 3)]);
        qfL[sl] = *reinterpret_cast<const s8v*>(&QpL[l16 * 128 + sl * 32 + (quad << 3)]);
    }
    s8v ones;
#pragma unroll
    for (int i = 0; i < 8; i++) ones[i] = (short)0x3F80;   // bf16 1.0

    // staging address components
    int krow = tid >> 4, kg = (tid & 15) ^ krow;
    int vd = tid >> 3, vg = (tid & 7) ^ (vd & 7);
    auto stage = [&](int t) {
        int kbt = t << 6;
        const u16* kgp = Kp + (size_t)(kbt + krow) * 128 + (kg << 3);
        const u16* vgp = Vp + (size_t)vd * 2048 + kbt + (vg << 3);
        char* kd = (char*)&Ks[t & 1][0];
        char* vdst = (char*)&Vs[t & 1][0];
#pragma unroll
        for (int i = 0; i < 4; i++) {
            gl_lds16(kgp + (size_t)(i << 4) * 128, kd + (i << 12) + tid * 16);
            gl_lds16(vgp + (size_t)(i << 5) * 2048, vdst + (i << 12) + tid * 16);
        }
    };

    f4v zero = {0.f, 0.f, 0.f, 0.f};
    f4v uH[8], uL[8], sumsH = zero, sumsL = zero;
#pragma unroll
    for (int ni = 0; ni < 8; ni++) { uH[ni] = zero; uL[ni] = zero; }
    float mpH[4], mpL[4], mcH[4], mcL[4], dH[4], dL[4];
#pragma unroll
    for (int r = 0; r < 4; r++) {
        mpH[r] = NINF; mpL[r] = NINF; mcH[r] = NINF; mcL[r] = NINF;
        dH[r] = 1.f; dL[r] = 1.f;
    }

    stage(0);
    for (int t = 0; t < nt; t++) {
        __syncthreads();             // drains loads(t) [issued last iter] + WAR fence
        if (t + 1 < nt) stage(t + 1);
        const char* Kbuf = (const char*)&Ks[t & 1][0];
        const char* Vbuf = (const char*)&Vs[t & 1][0];

        bool actL = (t <= diagL);
        int subsH = (t == diagH) ? (wv + 1) : 4;
        int subsL = actL ? ((t == diagL) ? (wv + 1) : 4) : 0;   // subsH >= subsL

        // ---- QK^T (shared kf) ----
        f4v scH[4], scL[4];
        float tmxH[4] = {NINF, NINF, NINF, NINF};
        float tmxL[4] = {NINF, NINF, NINF, NINF};
#pragma unroll
        for (int sub = 0; sub < 4; sub++) {
            if (sub >= subsH) continue;
            f4v sH = zero, sL = zero;
#pragma unroll
            for (int sl = 0; sl < 4; sl++) {
                s8v kf = *reinterpret_cast<const s8v*>(
                    Kbuf + ((sub << 4) + l16) * 256 + ((((sl << 2) + quad) ^ l16) << 4));
                sH = MFMA16(qfH[sl], kf, sH);
                if (sub < subsL) sL = MFMA16(qfL[sl], kf, sL);
            }
            bool partH = (t == diagH) && (sub == wv);
#pragma unroll
            for (int r = 0; r < 4; r++) {
                float v = sH[r] * scale;
                if (partH && (l16 > (quad << 2) + r)) v = NINF;
                scH[sub][r] = v;
                tmxH[r] = fmaxf(tmxH[r], v);
            }
            if (sub < subsL) {
                bool partL = (t == diagL) && (sub == wv);
#pragma unroll
                for (int r = 0; r < 4; r++) {
                    float v = sL[r] * scale;
                    if (partL && (l16 > (quad << 2) + r)) v = NINF;
                    scL[sub][r] = v;
                    tmxL[r] = fmaxf(tmxL[r], v);
                }
            }
        }
        // ---- running max update (+ conditional rescale) ----
        {
#pragma unroll
            for (int r = 0; r < 4; r++)
#pragma unroll
                for (int off = 1; off < 16; off <<= 1)
                    tmxH[r] = fmaxf(tmxH[r], __shfl_xor(tmxH[r], off));
            bool chg = false;
#pragma unroll
            for (int r = 0; r < 4; r++) chg |= (tmxH[r] > mcH[r]);
            if (__ballot(chg)) {
                float al[4];
#pragma unroll
                for (int r = 0; r < 4; r++) {
                    float nm = fmaxf(mcH[r], tmxH[r]);
                    al[r] = __expf(mcH[r] - nm);
                    mcH[r] = nm;
                    sumsH[r] *= al[r];
                }
#pragma unroll
                for (int ni = 0; ni < 8; ni++)
#pragma unroll
                    for (int r = 0; r < 4; r++) uH[ni][r] *= al[r];
            }
        }
        if (actL) {
#pragma unroll
            for (int r = 0; r < 4; r++)
#pragma unroll
                for (int off = 1; off < 16; off <<= 1)
                    tmxL[r] = fmaxf(tmxL[r], __shfl_xor(tmxL[r], off));
            bool chg = false;
#pragma unroll
            for (int r = 0; r < 4; r++) chg |= (tmxL[r] > mcL[r]);
            if (__ballot(chg)) {
                float al[4];
#pragma unroll
                for (int r = 0; r < 4; r++) {
                    float nm = fmaxf(mcL[r], tmxL[r]);
                    al[r] = __expf(mcL[r] - nm);
                    mcL[r] = nm;
                    sumsL[r] *= al[r];
                }
#pragma unroll
                for (int ni = 0; ni < 8; ni++)
#pragma unroll
                    for (int r = 0; r < 4; r++) uL[ni][r] *= al[r];
            }
        }
        // ---- exp -> Pb, PV + row-sum MFMAs (shared vf) ----
        int ns2H = (subsH + 1) >> 1, ns2L = (subsL + 1) >> 1;
#pragma unroll
        for (int s2 = 0; s2 < 2; s2++) {
            if (s2 >= ns2H) continue;
            bool doL2 = (s2 < ns2L);
#pragma unroll
            for (int half = 0; half < 2; half++) {
                int sub = (s2 << 1) + half;
#pragma unroll
                for (int r = 0; r < 4; r++) {
                    u16 eH = (sub < subsH) ? f2b(__expf(scH[sub][r] - mcH[r])) : (u16)0;
                    Pb[0][wv][(quad << 2) + r][(half << 4) + l16] = eH;
                }
                if (doL2) {
#pragma unroll
                    for (int r = 0; r < 4; r++) {
                        u16 eL = (sub < subsL) ? f2b(__expf(scL[sub][r] - mcL[r])) : (u16)0;
                        Pb[1][wv][(quad << 2) + r][(half << 4) + l16] = eL;
                    }
                }
            }
            // same-wave DS ordering: writes above visible to reads below
            s8v pfH = *reinterpret_cast<const s8v*>(&Pb[0][wv][l16][quad << 3]);
            sumsH = MFMA16(pfH, ones, sumsH);
            s8v pfL;
            if (doL2) {
                pfL = *reinterpret_cast<const s8v*>(&Pb[1][wv][l16][quad << 3]);
                sumsL = MFMA16(pfL, ones, sumsL);
            }
#pragma unroll
            for (int ni = 0; ni < 8; ni++) {
                s8v vf = *reinterpret_cast<const s8v*>(
                    Vbuf + ((ni << 4) + l16) * 128 + ((((s2 << 2) + quad) ^ (l16 & 7)) << 4));
                uH[ni] = MFMA16(pfH, vf, uH[ni]);
                if (doL2) uL[ni] = MFMA16(pfL, vf, uL[ni]);
            }
        }
        // ---- chunk close (matches reference scan step) ----
        if (((t & 7) == 7) || (t == diagH)) {
#pragma unroll
            for (int r = 0; r < 4; r++) {
                float p = __expf(mpH[r] - mcH[r]);
                float dd = p + sumsH[r];
                dH[r] = dd;
                float inv = 1.f / dd;
#pragma unroll
                for (int ni = 0; ni < 8; ni++) uH[ni][r] *= inv;
                mpH[r] = mcH[r];
            }
            sumsH = zero;
        }
        if (actL && (((t & 7) == 7) || (t == diagL))) {
#pragma unroll
            for (int r = 0; r < 4; r++) {
                float p = __expf(mpL[r] - mcL[r]);
                float dd = p + sumsL[r];
                dL[r] = dd;
                float inv = 1.f / dd;
#pragma unroll
                for (int ni = 0; ni < 8; ni++) uL[ni][r] *= inv;
                mpL[r] = mcL[r];
            }
            sumsL = zero;
        }
    }
    if (qtH >= 24) {   // rows in key-chunk 3: reference's final o/d double-divides
#pragma unroll
        for (int r = 0; r < 4; r++) {
            float inv = 1.f / dH[r];
#pragma unroll
            for (int ni = 0; ni < 8; ni++) uH[ni][r] *= inv;
        }
    }
    // qtL <= 15 < 24: final o/d divides by 1 (d carried from masked chunk 3)
#pragma unroll
    for (int ni = 0; ni < 8; ni++)
#pragma unroll
        for (int r = 0; r < 4; r++) {
            attnb[(size_t)(b * 2048 + qtH * 64 + wv * 16 + (quad << 2) + r) * 2048 +
                  h * 128 + ni * 16 + l16] = f2b(uH[ni][r]);
            attnb[(size_t)(b * 2048 + qtL * 64 + wv * 16 + (quad << 2) + r) * 2048 +
                  h * 128 + ni * 16 + l16] = f2b(uL[ni][r]);
        }
}

// ---------------------------------------------------------------------------
extern "C" void kernel_launch(void* const* d_in, const int* in_sizes, int n_in,
                              void* d_out, int out_size, void* d_ws, size_t ws_size,
                              hipStream_t stream) {
    (void)in_sizes; (void)n_in; (void)out_size; (void)ws_size;
    const float* hs = (const float*)d_in[0];
    // d_in[1] = attention_mask: causal additive, reconstructed analytically
    const float* Wq = (const float*)d_in[2];
    const float* bq = (const float*)d_in[3];
    const float* Wk = (const float*)d_in[4];
    const float* bk = (const float*)d_in[5];
    const float* Wv = (const float*)d_in[6];
    const float* bv = (const float*)d_in[7];
    const float* Wo = (const float*)d_in[8];
    const float* bo = (const float*)d_in[9];

    char* ws = (char*)d_ws;
    u16* hsb      = (u16*)(ws);                              // 16 MiB
    u16* qr       = hsb;                                     // reuse after GEMM1
    u16* wt_all   = (u16*)(ws + (16u << 20));                // 16 MiB
    u16* kr       = wt_all;                                  // reuse after GEMM1
    u16* vt       = (u16*)(ws + (24u << 20));                // 8 MiB
    u16* wo_t     = (u16*)(ws + (32u << 20));                // 8 MiB
    float* bias_c = (float*)(ws + (40u << 20));
    u16* qkv      = (u16*)(ws + (40u << 20) + 65536);        // 32 MiB
    u16* attnb    = qkv;                                     // reuse after rope/vtrans

    k_cast_hs<<<8192, 256, 0, stream>>>(hs, hsb);
    k_transpose_w<<<12288, 256, 0, stream>>>(Wq, Wk, Wv, Wo, wt_all, wo_t);
    k_bias<<<16, 256, 0, stream>>>(bq, bk, bv, bias_c);
    k_gemm<<<dim3(32, 32), 256, 0, stream>>>(hsb, wt_all, bias_c, qkv,
                                             4096, 4096, 2048, 0);
    k_rope<<<4096, 256, 0, stream>>>(qkv, qr, kr);
    k_vtrans<<<dim3(32, 4, 16), 256, 0, stream>>>(qkv, vt);
    k_attn<<<dim3(16, 16, 2), 256, 0, stream>>>(qr, kr, vt, attnb);
    k_gemm<<<dim3(16, 32), 256, 0, stream>>>(attnb, wo_t, bo, d_out,
                                             4096, 2048, 2048, 1);
}

// Round 4
// 452.609 us; speedup vs baseline: 6.0795x; 6.0795x over previous
//
#include <hip/hip_runtime.h>
#include <hip/hip_bf16.h>

// ---------------------------------------------------------------------------
// MemoryEfficientFlashAttention: B=2 S=2048 HID=2048 H=16 HKV=8 D=128 CHUNK=512
// R4: attention split into chunk-parallel partials + scalar combine.
//     R3 lesson: dual-stream register state spilled (8 GB scratch traffic) —
//     partials keep the proven R2 single-stream register budget (~110 VGPR)
//     and fix load balance by making work units near-uniform (<=8 key-tiles).
// ---------------------------------------------------------------------------

typedef __attribute__((ext_vector_type(8))) short s8v;   // 8 bf16 (4 VGPR) MFMA frag
typedef __attribute__((ext_vector_type(4))) float f4v;   // 4 fp32 acc frag

#define MFMA16(a, b, c) __builtin_amdgcn_mfma_f32_16x16x32_bf16((a), (b), (c), 0, 0, 0)

typedef unsigned short u16;
typedef const __attribute__((address_space(1))) unsigned int* gas_p;
typedef __attribute__((address_space(3))) unsigned int* las_p;

__device__ __forceinline__ void gl_lds16(const void* g, void* l) {
    __builtin_amdgcn_global_load_lds((gas_p)g, (las_p)l, 16, 0, 0);
}

__device__ __forceinline__ u16 f2b(float f) {
    __hip_bfloat16 h = __float2bfloat16(f);
    return *reinterpret_cast<u16*>(&h);
}
__device__ __forceinline__ float b2f(u16 u) {
    __hip_bfloat16 h;
    *reinterpret_cast<u16*>(&h) = u;
    return __bfloat162float(h);
}

// unit table: x -> (qt, c). 48 full-chunk units first (8 tiles each), then 32
// diagonal units in descending tile count. Slot index == x by construction.
__device__ const unsigned char qt_tab[80] = {
    8, 9, 10, 11, 12, 13, 14, 15,
    16, 16, 17, 17, 18, 18, 19, 19, 20, 20, 21, 21, 22, 22, 23, 23,
    24, 24, 24, 25, 25, 25, 26, 26, 26, 27, 27, 27,
    28, 28, 28, 29, 29, 29, 30, 30, 30, 31, 31, 31,
    31, 23, 15, 7, 30, 22, 14, 6, 29, 21, 13, 5, 28, 20, 12, 4,
    27, 19, 11, 3, 26, 18, 10, 2, 25, 17, 9, 1, 24, 16, 8, 0};
__device__ const unsigned char c_tab[80] = {
    0, 0, 0, 0, 0, 0, 0, 0,
    0, 1, 0, 1, 0, 1, 0, 1, 0, 1, 0, 1, 0, 1, 0, 1,
    0, 1, 2, 0, 1, 2, 0, 1, 2, 0, 1, 2,
    0, 1, 2, 0, 1, 2, 0, 1, 2, 0, 1, 2,
    3, 2, 1, 0, 3, 2, 1, 0, 3, 2, 1, 0, 3, 2, 1, 0,
    3, 2, 1, 0, 3, 2, 1, 0, 3, 2, 1, 0, 3, 2, 1, 0};

// inverse map (qt,c) -> unit/slot index (matches table order above)
__device__ __forceinline__ int uoff(int qt, int c) {
    int qc = qt >> 3;
    if (c < qc) {
        if (qt < 16) return qt - 8;
        if (qt < 24) return 8 + ((qt - 16) << 1) + c;
        return 24 + (qt - 24) * 3 + c;
    }
    return 48 + ((7 - (qt & 7)) << 2) + (3 - qc);
}

// ---------------- cast hidden_states fp32 -> bf16 ---------------------------
__global__ __launch_bounds__(256) void k_cast_hs(const float* __restrict__ src,
                                                 u16* __restrict__ dst) {
    int i = blockIdx.x * 256 + threadIdx.x;
    float4 v = reinterpret_cast<const float4*>(src)[i];
    alignas(8) u16 t[4] = {f2b(v.x), f2b(v.y), f2b(v.z), f2b(v.w)};
    reinterpret_cast<uint2*>(dst)[i] = *reinterpret_cast<uint2*>(t);
}

// ------------- transpose+cast weights: W[K][N] fp32 -> Wt[N][K] bf16 --------
__global__ __launch_bounds__(256) void k_transpose_w(
    const float* __restrict__ Wq, const float* __restrict__ Wk,
    const float* __restrict__ Wv, const float* __restrict__ Wo,
    u16* __restrict__ wt_all, u16* __restrict__ wo_t) {
    int id = blockIdx.x;
    const float* W; u16* dst; int N, nbase;
    if (id < 4096)      { W = Wq; dst = wt_all; N = 2048; nbase = 0; }
    else if (id < 6144) { W = Wk; dst = wt_all; N = 1024; nbase = 2048; id -= 4096; }
    else if (id < 8192) { W = Wv; dst = wt_all; N = 1024; nbase = 3072; id -= 6144; }
    else                { W = Wo; dst = wo_t;  N = 2048; nbase = 0;    id -= 8192; }
    int tiles_n = N >> 5;
    int k0 = (id / tiles_n) << 5, n0 = (id % tiles_n) << 5;
    __shared__ float t[32][33];
    int tid = threadIdx.x, c = tid & 31, rr = tid >> 5;
#pragma unroll
    for (int i = 0; i < 4; i++) {
        int kk = rr + i * 8;
        t[kk][c] = W[(size_t)(k0 + kk) * N + n0 + c];
    }
    __syncthreads();
#pragma unroll
    for (int i = 0; i < 4; i++) {
        int n = rr + i * 8;
        dst[(size_t)(nbase + n0 + n) * 2048 + k0 + c] = f2b(t[c][n]);
    }
}

// ---------------- concat biases bq|bk|bv -> fp32[4096] ----------------------
__global__ __launch_bounds__(256) void k_bias(const float* __restrict__ bq,
                                              const float* __restrict__ bk,
                                              const float* __restrict__ bv,
                                              float* __restrict__ dst) {
    int i = blockIdx.x * 256 + threadIdx.x;
    float v = (i < 2048) ? bq[i] : (i < 3072) ? bk[i - 2048] : bv[i - 3072];
    dst[i] = v;
}

// ---------------- bf16 MFMA GEMM: C[M][N] = A[M][K] * Bt[N][K]^T + bias -----
__global__ __launch_bounds__(256) void k_gemm(
    const u16* __restrict__ A, const u16* __restrict__ Bt,
    const float* __restrict__ bias, void* __restrict__ out,
    int M, int N, int K, int out_f32) {
    __shared__ alignas(16) u16 As[128][32];
    __shared__ alignas(16) u16 Bs[128][32];
    int tid = threadIdx.x;
    int wave = tid >> 6, lane = tid & 63, quad = lane >> 4, l16 = lane & 15;
    int m0 = blockIdx.y << 7, n0 = blockIdx.x << 7;
    int wm = (wave >> 1) << 6, wn = (wave & 1) << 6;
    f4v zero = {0.f, 0.f, 0.f, 0.f};
    f4v acc[4][4];
#pragma unroll
    for (int a = 0; a < 4; a++)
#pragma unroll
        for (int b = 0; b < 4; b++) acc[a][b] = zero;
    int r0 = tid >> 2, cb = (tid & 3) << 3;
    const u16* gA = A + (size_t)(m0 + r0) * K + cb;
    const u16* gB = Bt + (size_t)(n0 + r0) * K + cb;
    for (int k0 = 0; k0 < K; k0 += 32) {
        __syncthreads();
#pragma unroll
        for (int i = 0; i < 2; i++) {
            gl_lds16(gA + (size_t)(i << 6) * K + k0, (char*)As + (i << 12) + tid * 16);
            gl_lds16(gB + (size_t)(i << 6) * K + k0, (char*)Bs + (i << 12) + tid * 16);
        }
        __syncthreads();
        s8v af[4], bf_[4];
#pragma unroll
        for (int mi = 0; mi < 4; mi++)
            af[mi] = *reinterpret_cast<const s8v*>(&As[wm + mi * 16 + l16][quad << 3]);
#pragma unroll
        for (int ni = 0; ni < 4; ni++)
            bf_[ni] = *reinterpret_cast<const s8v*>(&Bs[wn + ni * 16 + l16][quad << 3]);
#pragma unroll
        for (int mi = 0; mi < 4; mi++)
#pragma unroll
            for (int ni = 0; ni < 4; ni++)
                acc[mi][ni] = MFMA16(af[mi], bf_[ni], acc[mi][ni]);
    }
#pragma unroll
    for (int mi = 0; mi < 4; mi++) {
#pragma unroll
        for (int ni = 0; ni < 4; ni++) {
            int n = n0 + wn + ni * 16 + l16;
            float bsv = bias[n];
#pragma unroll
            for (int r = 0; r < 4; r++) {
                int m = m0 + wm + mi * 16 + (quad << 2) + r;
                float v = acc[mi][ni][r] + bsv;
                if (out_f32)
                    reinterpret_cast<float*>(out)[(size_t)m * N + n] = v;
                else
                    reinterpret_cast<u16*>(out)[(size_t)m * N + n] = f2b(v);
            }
        }
    }
}

// ---------------- RoPE on Q and K, reshape to [B,H,S,D] ---------------------
__global__ __launch_bounds__(256) void k_rope(const u16* __restrict__ qkv,
                                              u16* __restrict__ qr,
                                              u16* __restrict__ kr) {
    int row = blockIdx.x;
    int b = row >> 11, s = row & 2047;
    const u16* src = qkv + (size_t)row * 4096;
    __shared__ float lcs[64], lsn[64];
    int tid = threadIdx.x;
    if (tid < 64) {
        float fr = (float)s * exp2f((float)tid * -0.31143075889569023f);
        lcs[tid] = cosf(fr);
        lsn[tid] = sinf(fr);
    }
    __syncthreads();
    for (int u = tid; u < 1536; u += 256) {
        int hh, i;
        const u16* sp;
        u16* dp;
        if (u < 1024) {
            hh = u >> 6; i = u & 63;
            sp = src + hh * 128;
            dp = qr + ((size_t)(b * 16 + hh) * 2048 + s) * 128;
        } else {
            int u2 = u - 1024;
            hh = u2 >> 6; i = u2 & 63;
            sp = src + 2048 + hh * 128;
            dp = kr + ((size_t)(b * 8 + hh) * 2048 + s) * 128;
        }
        float x1 = b2f(sp[i]);
        float x2 = b2f(sp[i + 64]);
        float cs = lcs[i], sn = lsn[i];
        dp[i]      = f2b(x1 * cs - x2 * sn);
        dp[i + 64] = f2b(x2 * cs + x1 * sn);
    }
}

// ---------------- V: reshape + transpose -> vt[B,HKV,D,S] bf16 --------------
__global__ __launch_bounds__(256) void k_vtrans(const u16* __restrict__ qkv,
                                                u16* __restrict__ vt) {
    int bkv = blockIdx.z, b = bkv >> 3, kv = bkv & 7;
    int s0 = blockIdx.x << 6, d0 = blockIdx.y << 5;
    __shared__ alignas(16) u16 t[32][72];
    int tid = threadIdx.x, c = tid & 31, rr = tid >> 5;
#pragma unroll
    for (int i = 0; i < 8; i++) {
        int s = s0 + rr + i * 8;
        t[c][rr + i * 8] = qkv[(size_t)(b * 2048 + s) * 4096 + 3072 + kv * 128 + d0 + c];
    }
    __syncthreads();
    int dd = tid >> 3, sc8 = (tid & 7) << 3;
    *reinterpret_cast<uint4*>(&vt[((size_t)(b * 8 + kv) * 128 + d0 + dd) * 2048 + s0 + sc8]) =
        *reinterpret_cast<const uint4*>(&t[dd][sc8]);
}

// ---------------- attention partials: one (b,h,qt,c) unit per block ---------
// Computes, over one 512-key chunk (or its causal prefix for diagonal units):
//   PV_hat = sum_k exp(s_k - c_hat) V_k   (bf16, unnormalized)
//   s_hat  = sum_k exp(s_k - c_hat)       (fp32)
//   c_hat  = max_k s_k                    (fp32)
// Single register stream (R2 structure): double-buffered global_load_lds K/V,
// one barrier/tile, ones-MFMA row sums, ballot-skipped rescale.
__global__ __launch_bounds__(256) void k_attn_part(const u16* __restrict__ qr,
                                                   const u16* __restrict__ kr,
                                                   const u16* __restrict__ vt,
                                                   u16* __restrict__ PVp,
                                                   float* __restrict__ scp) {
    const float scale = 0.08838834764831845f;   // 1/sqrt(128)
    const float NINF = -__builtin_inff();
    __shared__ alignas(16) u16 Ks[2][64 * 128];   // [key][dim], granule-swizzled
    __shared__ alignas(16) u16 Vs[2][128 * 64];   // [d][key],  granule-swizzled
    __shared__ alignas(16) u16 Pb[4][16][40];     // per-wave P buffer (+8 pad)

    int tid = threadIdx.x;
    int wv = tid >> 6, lane = tid & 63, quad = lane >> 4, l16 = lane & 15;
    int x = blockIdx.x, h = blockIdx.y, b = blockIdx.z, kvh = h >> 1;
    int qt = qt_tab[x], c = c_tab[x], qc = qt >> 3;
    int nt = (c < qc) ? 8 : (qt & 7) + 1;         // tiles in this unit
    int diagT = (c == qc) ? (qt & 7) : 8;         // diagonal tile idx (8 = none)
    int kbase = c << 9;
    const u16* Qp = qr + ((size_t)(b * 16 + h) * 2048 + qt * 64 + wv * 16) * 128;
    const u16* Kp = kr + ((size_t)(b * 8 + kvh) * 2048) * 128;
    const u16* Vp = vt + ((size_t)(b * 8 + kvh) * 128) * 2048;

    s8v qf[4];
#pragma unroll
    for (int sl = 0; sl < 4; sl++)
        qf[sl] = *reinterpret_cast<const s8v*>(&Qp[l16 * 128 + sl * 32 + (quad << 3)]);
    s8v ones;
#pragma unroll
    for (int i = 0; i < 8; i++) ones[i] = (short)0x3F80;   // bf16 1.0

    int krow = tid >> 4, kg = (tid & 15) ^ krow;
    int vd = tid >> 3, vg = (tid & 7) ^ (vd & 7);
    auto stage = [&](int t) {
        int kbt = kbase + (t << 6);
        const u16* kgp = Kp + (size_t)(kbt + krow) * 128 + (kg << 3);
        const u16* vgp = Vp + (size_t)vd * 2048 + kbt + (vg << 3);
        char* kd = (char*)&Ks[t & 1][0];
        char* vdst = (char*)&Vs[t & 1][0];
#pragma unroll
        for (int i = 0; i < 4; i++) {
            gl_lds16(kgp + (size_t)(i << 4) * 128, kd + (i << 12) + tid * 16);
            gl_lds16(vgp + (size_t)(i << 5) * 2048, vdst + (i << 12) + tid * 16);
        }
    };

    f4v zero = {0.f, 0.f, 0.f, 0.f};
    f4v u[8], sums = zero;
#pragma unroll
    for (int ni = 0; ni < 8; ni++) u[ni] = zero;
    float mc[4] = {NINF, NINF, NINF, NINF};

    stage(0);
    for (int t = 0; t < nt; t++) {
        __syncthreads();             // drains stage(t) loads + WAR fence
        if (t + 1 < nt) stage(t + 1);
        const char* Kbuf = (const char*)&Ks[t & 1][0];
        const char* Vbuf = (const char*)&Vs[t & 1][0];

        int subs = (t == diagT) ? (wv + 1) : 4;

        f4v sc[4];
        float tmx[4] = {NINF, NINF, NINF, NINF};
#pragma unroll
        for (int sub = 0; sub < 4; sub++) {
            if (sub >= subs) continue;
            f4v s = zero;
#pragma unroll
            for (int sl = 0; sl < 4; sl++) {
                s8v kf = *reinterpret_cast<const s8v*>(
                    Kbuf + ((sub << 4) + l16) * 256 + ((((sl << 2) + quad) ^ l16) << 4));
                s = MFMA16(qf[sl], kf, s);
            }
            bool part = (t == diagT) && (sub == wv);
#pragma unroll
            for (int r = 0; r < 4; r++) {
                float v = s[r] * scale;
                if (part && (l16 > (quad << 2) + r)) v = NINF;
                sc[sub][r] = v;
                tmx[r] = fmaxf(tmx[r], v);
            }
        }
#pragma unroll
        for (int r = 0; r < 4; r++)
#pragma unroll
            for (int off = 1; off < 16; off <<= 1)
                tmx[r] = fmaxf(tmx[r], __shfl_xor(tmx[r], off));
        bool chg = false;
#pragma unroll
        for (int r = 0; r < 4; r++) chg |= (tmx[r] > mc[r]);
        if (__ballot(chg)) {
            float al[4];
#pragma unroll
            for (int r = 0; r < 4; r++) {
                float nm = fmaxf(mc[r], tmx[r]);
                al[r] = __expf(mc[r] - nm);      // first tile: exp(-inf)=0
                mc[r] = nm;
                sums[r] *= al[r];
            }
#pragma unroll
            for (int ni = 0; ni < 8; ni++)
#pragma unroll
                for (int r = 0; r < 4; r++) u[ni][r] *= al[r];
        }
        int ns2 = (subs + 1) >> 1;
#pragma unroll
        for (int s2 = 0; s2 < 2; s2++) {
            if (s2 >= ns2) continue;
#pragma unroll
            for (int half = 0; half < 2; half++) {
                int sub = (s2 << 1) + half;
#pragma unroll
                for (int r = 0; r < 4; r++) {
                    u16 e = (sub < subs) ? f2b(__expf(sc[sub][r] - mc[r])) : (u16)0;
                    Pb[wv][(quad << 2) + r][(half << 4) + l16] = e;
                }
            }
            // same-wave DS ordering: writes above visible to reads below
            s8v pf = *reinterpret_cast<const s8v*>(&Pb[wv][l16][quad << 3]);
            sums = MFMA16(pf, ones, sums);
#pragma unroll
            for (int ni = 0; ni < 8; ni++) {
                s8v vf = *reinterpret_cast<const s8v*>(
                    Vbuf + ((ni << 4) + l16) * 128 + ((((s2 << 2) + quad) ^ (l16 & 7)) << 4));
                u[ni] = MFMA16(pf, vf, u[ni]);
            }
        }
    }
    // write partials (slot index == x by table construction)
    int slot = (b * 16 + h) * 80 + x;
    u16* pvdst = PVp + (size_t)slot * 8192;
#pragma unroll
    for (int ni = 0; ni < 8; ni++)
#pragma unroll
        for (int r = 0; r < 4; r++)
            pvdst[(wv * 16 + (quad << 2) + r) * 128 + ni * 16 + l16] = f2b(u[ni][r]);
    if (l16 == 0) {
        float* scd = scp + (size_t)slot * 128 + wv * 16 + (quad << 2);
#pragma unroll
        for (int r = 0; r < 4; r++) {
            scd[r] = mc[r];
            scd[64 + r] = sums[r];
        }
    }
}

// ---------------- combine partials with the exact reference scan step -------
// Per (b,h,qt): for c=0..qc:  m_c = max(m_prev, c_hat); p = exp(m_prev-m_c);
// lam = exp(c_hat-m_c); d = p + lam*s_hat; o = (o*p + lam*PV_hat)/d.
// Then the reference's trailing o/d: identity for qt<24 (d=1 on masked chunk),
// extra /d_3 for qt>=24.
__global__ __launch_bounds__(256) void k_attn_comb(const u16* __restrict__ PVp,
                                                   const float* __restrict__ scp,
                                                   u16* __restrict__ attnb) {
    int qt = blockIdx.x, h = blockIdx.y, b = blockIdx.z, qc = qt >> 3;
    int tid = threadIdx.x, row = tid >> 2, d0 = (tid & 3) << 5;
    int bh = b * 16 + h;
    float o[32];
#pragma unroll
    for (int i = 0; i < 32; i++) o[i] = 0.f;
    float mprev = -__builtin_inff(), dlast = 1.f;
    for (int cc = 0; cc <= qc; cc++) {
        int slot = bh * 80 + uoff(qt, cc);
        float ch = scp[(size_t)slot * 128 + row];
        float sh = scp[(size_t)slot * 128 + 64 + row];
        float mnew = fmaxf(mprev, ch);
        float p = __expf(mprev - mnew);      // cc==0: exp(-inf)=0
        float lam = __expf(ch - mnew);
        float dd = p + lam * sh;
        float inv = 1.f / dd;
        const u16* pv = PVp + (size_t)slot * 8192 + row * 128 + d0;
#pragma unroll
        for (int k = 0; k < 4; k++) {
            s8v v8 = *reinterpret_cast<const s8v*>(pv + (k << 3));
#pragma unroll
            for (int j = 0; j < 8; j++) {
                int i = (k << 3) + j;
                o[i] = (o[i] * p + lam * b2f((u16)v8[j])) * inv;
            }
        }
        mprev = mnew;
        dlast = dd;
    }
    if (qc == 3) {
        float inv = 1.f / dlast;
#pragma unroll
        for (int i = 0; i < 32; i++) o[i] *= inv;
    }
    alignas(16) u16 ob[32];
#pragma unroll
    for (int i = 0; i < 32; i++) ob[i] = f2b(o[i]);
    u16* dst = attnb + (size_t)(b * 2048 + qt * 64 + row) * 2048 + h * 128 + d0;
#pragma unroll
    for (int k = 0; k < 4; k++)
        reinterpret_cast<uint4*>(dst)[k] = reinterpret_cast<const uint4*>(ob)[k];
}

// ---------------------------------------------------------------------------
extern "C" void kernel_launch(void* const* d_in, const int* in_sizes, int n_in,
                              void* d_out, int out_size, void* d_ws, size_t ws_size,
                              hipStream_t stream) {
    (void)in_sizes; (void)n_in; (void)out_size; (void)ws_size;
    const float* hs = (const float*)d_in[0];
    // d_in[1] = attention_mask: causal additive, reconstructed analytically
    const float* Wq = (const float*)d_in[2];
    const float* bq = (const float*)d_in[3];
    const float* Wk = (const float*)d_in[4];
    const float* bk = (const float*)d_in[5];
    const float* Wv = (const float*)d_in[6];
    const float* bv = (const float*)d_in[7];
    const float* Wo = (const float*)d_in[8];
    const float* bo = (const float*)d_in[9];

    char* ws = (char*)d_ws;
    // layout (phases are stream-sequential; aliases noted):
    u16* hsb      = (u16*)(ws);                              // 16 MiB
    u16* qr       = hsb;                                     // alias after GEMM1
    u16* attnb    = hsb;                                     // alias after partials
    u16* wt_all   = (u16*)(ws + (16u << 20));                // 16 MiB
    u16* kr       = wt_all;                                  // alias after GEMM1
    u16* vt       = (u16*)(ws + (24u << 20));                // 8 MiB
    u16* wo_t     = (u16*)(ws + (32u << 20));                // 8 MiB
    float* bias_c = (float*)(ws + (40u << 20));              // 64 KiB
    u16* qkv      = (u16*)(ws + (40u << 20) + 65536);        // 32 MiB
    u16* PVp      = qkv;                                     // alias after rope/vtrans, 40 MiB
    float* scp    = (float*)(ws + (40u << 20) + 65536 + 41943040u);  // 1.25 MiB

    k_cast_hs<<<8192, 256, 0, stream>>>(hs, hsb);
    k_transpose_w<<<12288, 256, 0, stream>>>(Wq, Wk, Wv, Wo, wt_all, wo_t);
    k_bias<<<16, 256, 0, stream>>>(bq, bk, bv, bias_c);
    k_gemm<<<dim3(32, 32), 256, 0, stream>>>(hsb, wt_all, bias_c, qkv,
                                             4096, 4096, 2048, 0);
    k_rope<<<4096, 256, 0, stream>>>(qkv, qr, kr);
    k_vtrans<<<dim3(32, 4, 16), 256, 0, stream>>>(qkv, vt);
    k_attn_part<<<dim3(80, 16, 2), 256, 0, stream>>>(qr, kr, vt, PVp, scp);
    k_attn_comb<<<dim3(32, 16, 2), 256, 0, stream>>>(PVp, scp, attnb);
    k_gemm<<<dim3(16, 32), 256, 0, stream>>>(attnb, wo_t, bo, d_out,
                                             4096, 2048, 2048, 1);
}

// Round 5
// 430.900 us; speedup vs baseline: 6.3857x; 1.0504x over previous
//
#include <hip/hip_runtime.h>
#include <hip/hip_bf16.h>

// ---------------------------------------------------------------------------
// MemoryEfficientFlashAttention: B=2 S=2048 HID=2048 H=16 HKV=8 D=128 CHUNK=512
// R5: (a) GEMM LDS granule XOR-swizzle — kills the 4-way ds_read_b128 bank
//     conflict (8.4M conflict-cycles in R4); (b) attn partials accumulate at
//     fixed reference point (no per-tile rescale/reduce; single rescale at
//     unit end), Q pre-scaled by scale*log2e so scores emerge in exp2 domain.
// ---------------------------------------------------------------------------

typedef __attribute__((ext_vector_type(8))) short s8v;   // 8 bf16 (4 VGPR) MFMA frag
typedef __attribute__((ext_vector_type(4))) float f4v;   // 4 fp32 acc frag

#define MFMA16(a, b, c) __builtin_amdgcn_mfma_f32_16x16x32_bf16((a), (b), (c), 0, 0, 0)

typedef unsigned short u16;
typedef const __attribute__((address_space(1))) unsigned int* gas_p;
typedef __attribute__((address_space(3))) unsigned int* las_p;

__device__ __forceinline__ void gl_lds16(const void* g, void* l) {
    __builtin_amdgcn_global_load_lds((gas_p)g, (las_p)l, 16, 0, 0);
}

__device__ __forceinline__ u16 f2b(float f) {
    __hip_bfloat16 h = __float2bfloat16(f);
    return *reinterpret_cast<u16*>(&h);
}
__device__ __forceinline__ float b2f(u16 u) {
    __hip_bfloat16 h;
    *reinterpret_cast<u16*>(&h) = u;
    return __bfloat162float(h);
}

// unit table: x -> (qt, c). 48 full-chunk units first (8 tiles each), then 32
// diagonal units in descending tile count. Slot index == x by construction.
__device__ const unsigned char qt_tab[80] = {
    8, 9, 10, 11, 12, 13, 14, 15,
    16, 16, 17, 17, 18, 18, 19, 19, 20, 20, 21, 21, 22, 22, 23, 23,
    24, 24, 24, 25, 25, 25, 26, 26, 26, 27, 27, 27,
    28, 28, 28, 29, 29, 29, 30, 30, 30, 31, 31, 31,
    31, 23, 15, 7, 30, 22, 14, 6, 29, 21, 13, 5, 28, 20, 12, 4,
    27, 19, 11, 3, 26, 18, 10, 2, 25, 17, 9, 1, 24, 16, 8, 0};
__device__ const unsigned char c_tab[80] = {
    0, 0, 0, 0, 0, 0, 0, 0,
    0, 1, 0, 1, 0, 1, 0, 1, 0, 1, 0, 1, 0, 1, 0, 1,
    0, 1, 2, 0, 1, 2, 0, 1, 2, 0, 1, 2,
    0, 1, 2, 0, 1, 2, 0, 1, 2, 0, 1, 2,
    3, 2, 1, 0, 3, 2, 1, 0, 3, 2, 1, 0, 3, 2, 1, 0,
    3, 2, 1, 0, 3, 2, 1, 0, 3, 2, 1, 0, 3, 2, 1, 0};

// inverse map (qt,c) -> unit/slot index (matches table order above)
__device__ __forceinline__ int uoff(int qt, int c) {
    int qc = qt >> 3;
    if (c < qc) {
        if (qt < 16) return qt - 8;
        if (qt < 24) return 8 + ((qt - 16) << 1) + c;
        return 24 + (qt - 24) * 3 + c;
    }
    return 48 + ((7 - (qt & 7)) << 2) + (3 - qc);
}

// ---------------- cast hidden_states fp32 -> bf16 ---------------------------
__global__ __launch_bounds__(256) void k_cast_hs(const float* __restrict__ src,
                                                 u16* __restrict__ dst) {
    int i = blockIdx.x * 256 + threadIdx.x;
    float4 v = reinterpret_cast<const float4*>(src)[i];
    alignas(8) u16 t[4] = {f2b(v.x), f2b(v.y), f2b(v.z), f2b(v.w)};
    reinterpret_cast<uint2*>(dst)[i] = *reinterpret_cast<uint2*>(t);
}

// ------------- transpose+cast weights: W[K][N] fp32 -> Wt[N][K] bf16 --------
__global__ __launch_bounds__(256) void k_transpose_w(
    const float* __restrict__ Wq, const float* __restrict__ Wk,
    const float* __restrict__ Wv, const float* __restrict__ Wo,
    u16* __restrict__ wt_all, u16* __restrict__ wo_t) {
    int id = blockIdx.x;
    const float* W; u16* dst; int N, nbase;
    if (id < 4096)      { W = Wq; dst = wt_all; N = 2048; nbase = 0; }
    else if (id < 6144) { W = Wk; dst = wt_all; N = 1024; nbase = 2048; id -= 4096; }
    else if (id < 8192) { W = Wv; dst = wt_all; N = 1024; nbase = 3072; id -= 6144; }
    else                { W = Wo; dst = wo_t;  N = 2048; nbase = 0;    id -= 8192; }
    int tiles_n = N >> 5;
    int k0 = (id / tiles_n) << 5, n0 = (id % tiles_n) << 5;
    __shared__ float t[32][33];
    int tid = threadIdx.x, c = tid & 31, rr = tid >> 5;
#pragma unroll
    for (int i = 0; i < 4; i++) {
        int kk = rr + i * 8;
        t[kk][c] = W[(size_t)(k0 + kk) * N + n0 + c];
    }
    __syncthreads();
#pragma unroll
    for (int i = 0; i < 4; i++) {
        int n = rr + i * 8;
        dst[(size_t)(nbase + n0 + n) * 2048 + k0 + c] = f2b(t[c][n]);
    }
}

// ---------------- concat biases bq|bk|bv -> fp32[4096] ----------------------
__global__ __launch_bounds__(256) void k_bias(const float* __restrict__ bq,
                                              const float* __restrict__ bk,
                                              const float* __restrict__ bv,
                                              float* __restrict__ dst) {
    int i = blockIdx.x * 256 + threadIdx.x;
    float v = (i < 2048) ? bq[i] : (i < 3072) ? bk[i - 2048] : bv[i - 3072];
    dst[i] = v;
}

// ---------------- bf16 MFMA GEMM: C[M][N] = A[M][K] * Bt[N][K]^T + bias -----
// 128x128 tile, BK=32, global_load_lds staging. LDS granule (16B) swizzled by
// (row>>1)&3 so each ds_read_b128 16-lane sub-access covers all 32 banks
// (2-way = free) instead of R4's 4-way conflict.
__global__ __launch_bounds__(256) void k_gemm(
    const u16* __restrict__ A, const u16* __restrict__ Bt,
    const float* __restrict__ bias, void* __restrict__ out,
    int M, int N, int K, int out_f32) {
    __shared__ alignas(16) u16 As[128][32];
    __shared__ alignas(16) u16 Bs[128][32];
    int tid = threadIdx.x;
    int wave = tid >> 6, lane = tid & 63, quad = lane >> 4, l16 = lane & 15;
    int m0 = blockIdx.y << 7, n0 = blockIdx.x << 7;
    int wm = (wave >> 1) << 6, wn = (wave & 1) << 6;
    f4v zero = {0.f, 0.f, 0.f, 0.f};
    f4v acc[4][4];
#pragma unroll
    for (int a = 0; a < 4; a++)
#pragma unroll
        for (int b = 0; b < 4; b++) acc[a][b] = zero;
    int r0 = tid >> 2;
    int gsw = (tid & 3) ^ ((r0 >> 1) & 3);        // swizzled source granule
    const u16* gA = A + (size_t)(m0 + r0) * K + (gsw << 3);
    const u16* gB = Bt + (size_t)(n0 + r0) * K + (gsw << 3);
    int rg = (quad ^ ((l16 >> 1) & 3)) << 3;      // swizzled read granule
    for (int k0 = 0; k0 < K; k0 += 32) {
        __syncthreads();
#pragma unroll
        for (int i = 0; i < 2; i++) {
            gl_lds16(gA + (size_t)(i << 6) * K + k0, (char*)As + (i << 12) + tid * 16);
            gl_lds16(gB + (size_t)(i << 6) * K + k0, (char*)Bs + (i << 12) + tid * 16);
        }
        __syncthreads();
        s8v af[4], bf_[4];
#pragma unroll
        for (int mi = 0; mi < 4; mi++)
            af[mi] = *reinterpret_cast<const s8v*>(&As[wm + mi * 16 + l16][rg]);
#pragma unroll
        for (int ni = 0; ni < 4; ni++)
            bf_[ni] = *reinterpret_cast<const s8v*>(&Bs[wn + ni * 16 + l16][rg]);
#pragma unroll
        for (int mi = 0; mi < 4; mi++)
#pragma unroll
            for (int ni = 0; ni < 4; ni++)
                acc[mi][ni] = MFMA16(af[mi], bf_[ni], acc[mi][ni]);
    }
#pragma unroll
    for (int mi = 0; mi < 4; mi++) {
#pragma unroll
        for (int ni = 0; ni < 4; ni++) {
            int n = n0 + wn + ni * 16 + l16;
            float bsv = bias[n];
#pragma unroll
            for (int r = 0; r < 4; r++) {
                int m = m0 + wm + mi * 16 + (quad << 2) + r;
                float v = acc[mi][ni][r] + bsv;
                if (out_f32)
                    reinterpret_cast<float*>(out)[(size_t)m * N + n] = v;
                else
                    reinterpret_cast<u16*>(out)[(size_t)m * N + n] = f2b(v);
            }
        }
    }
}

// ---------------- RoPE on Q and K, reshape to [B,H,S,D] ---------------------
// Q additionally pre-scaled by scale*log2e so QK^T emerges in exp2 domain.
__global__ __launch_bounds__(256) void k_rope(const u16* __restrict__ qkv,
                                              u16* __restrict__ qr,
                                              u16* __restrict__ kr) {
    const float qscale = 0.08838834764831845f * 1.44269504088896340f;
    int row = blockIdx.x;
    int b = row >> 11, s = row & 2047;
    const u16* src = qkv + (size_t)row * 4096;
    __shared__ float lcs[64], lsn[64];
    int tid = threadIdx.x;
    if (tid < 64) {
        float fr = (float)s * exp2f((float)tid * -0.31143075889569023f);
        lcs[tid] = cosf(fr);
        lsn[tid] = sinf(fr);
    }
    __syncthreads();
    for (int u = tid; u < 1536; u += 256) {
        int hh, i;
        const u16* sp;
        u16* dp;
        float sc;
        if (u < 1024) {
            hh = u >> 6; i = u & 63;
            sp = src + hh * 128;
            dp = qr + ((size_t)(b * 16 + hh) * 2048 + s) * 128;
            sc = qscale;
        } else {
            int u2 = u - 1024;
            hh = u2 >> 6; i = u2 & 63;
            sp = src + 2048 + hh * 128;
            dp = kr + ((size_t)(b * 8 + hh) * 2048 + s) * 128;
            sc = 1.f;
        }
        float x1 = b2f(sp[i]);
        float x2 = b2f(sp[i + 64]);
        float cs = lcs[i], sn = lsn[i];
        dp[i]      = f2b((x1 * cs - x2 * sn) * sc);
        dp[i + 64] = f2b((x2 * cs + x1 * sn) * sc);
    }
}

// ---------------- V: reshape + transpose -> vt[B,HKV,D,S] bf16 --------------
__global__ __launch_bounds__(256) void k_vtrans(const u16* __restrict__ qkv,
                                                u16* __restrict__ vt) {
    int bkv = blockIdx.z, b = bkv >> 3, kv = bkv & 7;
    int s0 = blockIdx.x << 6, d0 = blockIdx.y << 5;
    __shared__ alignas(16) u16 t[32][72];
    int tid = threadIdx.x, c = tid & 31, rr = tid >> 5;
#pragma unroll
    for (int i = 0; i < 8; i++) {
        int s = s0 + rr + i * 8;
        t[c][rr + i * 8] = qkv[(size_t)(b * 2048 + s) * 4096 + 3072 + kv * 128 + d0 + c];
    }
    __syncthreads();
    int dd = tid >> 3, sc8 = (tid & 7) << 3;
    *reinterpret_cast<uint4*>(&vt[((size_t)(b * 8 + kv) * 128 + d0 + dd) * 2048 + s0 + sc8]) =
        *reinterpret_cast<const uint4*>(&t[dd][sc8]);
}

// ---------------- attention partials: one (b,h,qt,c) unit per block ---------
// Fixed-reference accumulation: u = sum e^s V, sums = sum e^s (s in exp2
// domain via pre-scaled Q; no per-tile max/rescale). Per-lane running max
// reduced and applied ONCE at unit end:
//   PV_hat = u * 2^-mhat, s_hat = sums * 2^-mhat, c_hat = mhat * ln2.
// Combine is invariant to the chunk-internal reference; c_hat is the true max.
__global__ __launch_bounds__(256) void k_attn_part(const u16* __restrict__ qr,
                                                   const u16* __restrict__ kr,
                                                   const u16* __restrict__ vt,
                                                   u16* __restrict__ PVp,
                                                   float* __restrict__ scp) {
    const float NINF = -__builtin_inff();
    __shared__ alignas(16) u16 Ks[2][64 * 128];   // [key][dim], granule-swizzled
    __shared__ alignas(16) u16 Vs[2][128 * 64];   // [d][key],  granule-swizzled
    __shared__ alignas(16) u16 Pb[4][16][40];     // per-wave P buffer (+8 pad)

    int tid = threadIdx.x;
    int wv = tid >> 6, lane = tid & 63, quad = lane >> 4, l16 = lane & 15;
    int x = blockIdx.x, h = blockIdx.y, b = blockIdx.z, kvh = h >> 1;
    int qt = qt_tab[x], c = c_tab[x], qc = qt >> 3;
    int nt = (c < qc) ? 8 : (qt & 7) + 1;         // tiles in this unit
    int diagT = (c == qc) ? (qt & 7) : 8;         // diagonal tile idx (8 = none)
    int kbase = c << 9;
    const u16* Qp = qr + ((size_t)(b * 16 + h) * 2048 + qt * 64 + wv * 16) * 128;
    const u16* Kp = kr + ((size_t)(b * 8 + kvh) * 2048) * 128;
    const u16* Vp = vt + ((size_t)(b * 8 + kvh) * 128) * 2048;

    s8v qf[4];
#pragma unroll
    for (int sl = 0; sl < 4; sl++)
        qf[sl] = *reinterpret_cast<const s8v*>(&Qp[l16 * 128 + sl * 32 + (quad << 3)]);
    s8v ones;
#pragma unroll
    for (int i = 0; i < 8; i++) ones[i] = (short)0x3F80;   // bf16 1.0

    int krow = tid >> 4, kg = (tid & 15) ^ krow;
    int vd = tid >> 3, vg = (tid & 7) ^ (vd & 7);
    auto stage = [&](int t) {
        int kbt = kbase + (t << 6);
        const u16* kgp = Kp + (size_t)(kbt + krow) * 128 + (kg << 3);
        const u16* vgp = Vp + (size_t)vd * 2048 + kbt + (vg << 3);
        char* kd = (char*)&Ks[t & 1][0];
        char* vdst = (char*)&Vs[t & 1][0];
#pragma unroll
        for (int i = 0; i < 4; i++) {
            gl_lds16(kgp + (size_t)(i << 4) * 128, kd + (i << 12) + tid * 16);
            gl_lds16(vgp + (size_t)(i << 5) * 2048, vdst + (i << 12) + tid * 16);
        }
    };

    f4v zero = {0.f, 0.f, 0.f, 0.f};
    f4v u[8], sums = zero;
#pragma unroll
    for (int ni = 0; ni < 8; ni++) u[ni] = zero;
    float tmx[4] = {NINF, NINF, NINF, NINF};      // per-lane running max (exp2 dom)

    stage(0);
    for (int t = 0; t < nt; t++) {
        __syncthreads();             // drains stage(t) loads + WAR fence
        if (t + 1 < nt) stage(t + 1);
        const char* Kbuf = (const char*)&Ks[t & 1][0];
        const char* Vbuf = (const char*)&Vs[t & 1][0];

        int subs = (t == diagT) ? (wv + 1) : 4;
        int ns2 = (subs + 1) >> 1;
#pragma unroll
        for (int s2 = 0; s2 < 2; s2++) {
            if (s2 >= ns2) continue;
#pragma unroll
            for (int half = 0; half < 2; half++) {
                int sub = (s2 << 1) + half;
                if (sub >= subs) {    // fully masked sub inside active pair
#pragma unroll
                    for (int r = 0; r < 4; r++)
                        Pb[wv][(quad << 2) + r][(half << 4) + l16] = (u16)0;
                    continue;
                }
                f4v s = zero;
#pragma unroll
                for (int sl = 0; sl < 4; sl++) {
                    s8v kf = *reinterpret_cast<const s8v*>(
                        Kbuf + ((sub << 4) + l16) * 256 + ((((sl << 2) + quad) ^ l16) << 4));
                    s = MFMA16(qf[sl], kf, s);
                }
                bool part = (t == diagT) && (sub == wv);
#pragma unroll
                for (int r = 0; r < 4; r++) {
                    float v = s[r];
                    if (part && (l16 > (quad << 2) + r)) v = NINF;
                    tmx[r] = fmaxf(tmx[r], v);
                    float e = __builtin_amdgcn_exp2f(v);   // exp2(NINF)=0
                    Pb[wv][(quad << 2) + r][(half << 4) + l16] = f2b(e);
                }
            }
            // same-wave DS ordering: writes above visible to reads below
            s8v pf = *reinterpret_cast<const s8v*>(&Pb[wv][l16][quad << 3]);
            sums = MFMA16(pf, ones, sums);
#pragma unroll
            for (int ni = 0; ni < 8; ni++) {
                s8v vf = *reinterpret_cast<const s8v*>(
                    Vbuf + ((ni << 4) + l16) * 128 + ((((s2 << 2) + quad) ^ (l16 & 7)) << 4));
                u[ni] = MFMA16(pf, vf, u[ni]);
            }
        }
    }
    // one-time reduce + rescale
#pragma unroll
    for (int r = 0; r < 4; r++)
#pragma unroll
        for (int off = 1; off < 16; off <<= 1)
            tmx[r] = fmaxf(tmx[r], __shfl_xor(tmx[r], off));
    float resc[4];
#pragma unroll
    for (int r = 0; r < 4; r++) resc[r] = __builtin_amdgcn_exp2f(-tmx[r]);

    int slot = (b * 16 + h) * 80 + x;
    u16* pvdst = PVp + (size_t)slot * 8192;
#pragma unroll
    for (int ni = 0; ni < 8; ni++)
#pragma unroll
        for (int r = 0; r < 4; r++)
            pvdst[(wv * 16 + (quad << 2) + r) * 128 + ni * 16 + l16] =
                f2b(u[ni][r] * resc[r]);
    if (l16 == 0) {
        float* scd = scp + (size_t)slot * 128 + wv * 16 + (quad << 2);
#pragma unroll
        for (int r = 0; r < 4; r++) {
            scd[r] = tmx[r] * 0.6931471805599453f;   // back to natural log dom
            scd[64 + r] = sums[r] * resc[r];
        }
    }
}

// ---------------- combine partials with the exact reference scan step -------
__global__ __launch_bounds__(256) void k_attn_comb(const u16* __restrict__ PVp,
                                                   const float* __restrict__ scp,
                                                   u16* __restrict__ attnb) {
    int qt = blockIdx.x, h = blockIdx.y, b = blockIdx.z, qc = qt >> 3;
    int tid = threadIdx.x, row = tid >> 2, d0 = (tid & 3) << 5;
    int bh = b * 16 + h;
    float o[32];
#pragma unroll
    for (int i = 0; i < 32; i++) o[i] = 0.f;
    float mprev = -__builtin_inff(), dlast = 1.f;
    for (int cc = 0; cc <= qc; cc++) {
        int slot = bh * 80 + uoff(qt, cc);
        float ch = scp[(size_t)slot * 128 + row];
        float sh = scp[(size_t)slot * 128 + 64 + row];
        float mnew = fmaxf(mprev, ch);
        float p = __expf(mprev - mnew);      // cc==0: exp(-inf)=0
        float lam = __expf(ch - mnew);
        float dd = p + lam * sh;
        float inv = 1.f / dd;
        const u16* pv = PVp + (size_t)slot * 8192 + row * 128 + d0;
#pragma unroll
        for (int k = 0; k < 4; k++) {
            s8v v8 = *reinterpret_cast<const s8v*>(pv + (k << 3));
#pragma unroll
            for (int j = 0; j < 8; j++) {
                int i = (k << 3) + j;
                o[i] = (o[i] * p + lam * b2f((u16)v8[j])) * inv;
            }
        }
        mprev = mnew;
        dlast = dd;
    }
    if (qc == 3) {
        float inv = 1.f / dlast;
#pragma unroll
        for (int i = 0; i < 32; i++) o[i] *= inv;
    }
    alignas(16) u16 ob[32];
#pragma unroll
    for (int i = 0; i < 32; i++) ob[i] = f2b(o[i]);
    u16* dst = attnb + (size_t)(b * 2048 + qt * 64 + row) * 2048 + h * 128 + d0;
#pragma unroll
    for (int k = 0; k < 4; k++)
        reinterpret_cast<uint4*>(dst)[k] = reinterpret_cast<const uint4*>(ob)[k];
}

// ---------------------------------------------------------------------------
extern "C" void kernel_launch(void* const* d_in, const int* in_sizes, int n_in,
                              void* d_out, int out_size, void* d_ws, size_t ws_size,
                              hipStream_t stream) {
    (void)in_sizes; (void)n_in; (void)out_size; (void)ws_size;
    const float* hs = (const float*)d_in[0];
    // d_in[1] = attention_mask: causal additive, reconstructed analytically
    const float* Wq = (const float*)d_in[2];
    const float* bq = (const float*)d_in[3];
    const float* Wk = (const float*)d_in[4];
    const float* bk = (const float*)d_in[5];
    const float* Wv = (const float*)d_in[6];
    const float* bv = (const float*)d_in[7];
    const float* Wo = (const float*)d_in[8];
    const float* bo = (const float*)d_in[9];

    char* ws = (char*)d_ws;
    u16* hsb      = (u16*)(ws);                              // 16 MiB
    u16* qr       = hsb;                                     // alias after GEMM1
    u16* attnb    = hsb;                                     // alias after partials
    u16* wt_all   = (u16*)(ws + (16u << 20));                // 16 MiB
    u16* kr       = wt_all;                                  // alias after GEMM1
    u16* vt       = (u16*)(ws + (24u << 20));                // 8 MiB
    u16* wo_t     = (u16*)(ws + (32u << 20));                // 8 MiB
    float* bias_c = (float*)(ws + (40u << 20));              // 64 KiB
    u16* qkv      = (u16*)(ws + (40u << 20) + 65536);        // 32 MiB
    u16* PVp      = qkv;                                     // alias, 40 MiB
    float* scp    = (float*)(ws + (40u << 20) + 65536 + 41943040u);  // 1.25 MiB

    k_cast_hs<<<8192, 256, 0, stream>>>(hs, hsb);
    k_transpose_w<<<12288, 256, 0, stream>>>(Wq, Wk, Wv, Wo, wt_all, wo_t);
    k_bias<<<16, 256, 0, stream>>>(bq, bk, bv, bias_c);
    k_gemm<<<dim3(32, 32), 256, 0, stream>>>(hsb, wt_all, bias_c, qkv,
                                             4096, 4096, 2048, 0);
    k_rope<<<4096, 256, 0, stream>>>(qkv, qr, kr);
    k_vtrans<<<dim3(32, 4, 16), 256, 0, stream>>>(qkv, vt);
    k_attn_part<<<dim3(80, 16, 2), 256, 0, stream>>>(qr, kr, vt, PVp, scp);
    k_attn_comb<<<dim3(32, 16, 2), 256, 0, stream>>>(PVp, scp, attnb);
    k_gemm<<<dim3(16, 32), 256, 0, stream>>>(attnb, wo_t, bo, d_out,
                                             4096, 2048, 2048, 1);
}

// Round 6
// 412.900 us; speedup vs baseline: 6.6641x; 1.0436x over previous
//
#include <hip/hip_runtime.h>
#include <hip/hip_bf16.h>

// ---------------------------------------------------------------------------
// MemoryEfficientFlashAttention: B=2 S=2048 HID=2048 H=16 HKV=8 D=128 CHUNK=512
// R6: (a) attn partials: 32 q-rows/wave (128-row q-tiles) — every K/V LDS frag
//     read now feeds 2 MFMAs, halving the ds_read_b128 cost per unit work;
//     (b) GEMM BK=64 — 32 MFMA per barrier pair instead of 16;
//     (c) transpose_w vectorized.
// ---------------------------------------------------------------------------

typedef __attribute__((ext_vector_type(8))) short s8v;   // 8 bf16 (4 VGPR) MFMA frag
typedef __attribute__((ext_vector_type(4))) float f4v;   // 4 fp32 acc frag

#define MFMA16(a, b, c) __builtin_amdgcn_mfma_f32_16x16x32_bf16((a), (b), (c), 0, 0, 0)

typedef unsigned short u16;
typedef const __attribute__((address_space(1))) unsigned int* gas_p;
typedef __attribute__((address_space(3))) unsigned int* las_p;

__device__ __forceinline__ void gl_lds16(const void* g, void* l) {
    __builtin_amdgcn_global_load_lds((gas_p)g, (las_p)l, 16, 0, 0);
}

__device__ __forceinline__ u16 f2b(float f) {
    __hip_bfloat16 h = __float2bfloat16(f);
    return *reinterpret_cast<u16*>(&h);
}
__device__ __forceinline__ float b2f(u16 u) {
    __hip_bfloat16 h;
    *reinterpret_cast<u16*>(&h) = u;
    return __bfloat162float(h);
}

// unit table: x -> (qt128, c). qt128 in 0..15 (128-row q-tiles), qc = qt>>2.
// 24 full-chunk units (8 tiles) first, then 16 diag units desc (8,6,4,2 tiles).
__device__ const unsigned char qt_tab[40] = {
    4, 5, 6, 7,
    8, 8, 9, 9, 10, 10, 11, 11,
    12, 12, 12, 13, 13, 13, 14, 14, 14, 15, 15, 15,
    3, 7, 11, 15, 2, 6, 10, 14, 1, 5, 9, 13, 0, 4, 8, 12};
__device__ const unsigned char c_tab[40] = {
    0, 0, 0, 0,
    0, 1, 0, 1, 0, 1, 0, 1,
    0, 1, 2, 0, 1, 2, 0, 1, 2, 0, 1, 2,
    0, 1, 2, 3, 0, 1, 2, 3, 0, 1, 2, 3, 0, 1, 2, 3};

// inverse map (qt128, c) -> unit/slot index
__device__ __forceinline__ int uoff40(int qt, int c) {
    int qc = qt >> 2;
    if (c < qc) {
        if (qt < 8) return qt - 4;
        if (qt < 12) return 4 + ((qt - 8) << 1) + c;
        return 12 + (qt - 12) * 3 + c;
    }
    return 24 + ((3 - (qt & 3)) << 2) + qc;
}

// ---------------- cast hidden_states fp32 -> bf16 ---------------------------
__global__ __launch_bounds__(256) void k_cast_hs(const float* __restrict__ src,
                                                 u16* __restrict__ dst) {
    int i = blockIdx.x * 256 + threadIdx.x;
    float4 v = reinterpret_cast<const float4*>(src)[i];
    alignas(8) u16 t[4] = {f2b(v.x), f2b(v.y), f2b(v.z), f2b(v.w)};
    reinterpret_cast<uint2*>(dst)[i] = *reinterpret_cast<uint2*>(t);
}

// ------------- transpose+cast weights: W[K][N] fp32 -> Wt[N][K] bf16 --------
__global__ __launch_bounds__(256) void k_transpose_w(
    const float* __restrict__ Wq, const float* __restrict__ Wk,
    const float* __restrict__ Wv, const float* __restrict__ Wo,
    u16* __restrict__ wt_all, u16* __restrict__ wo_t) {
    int id = blockIdx.x;
    const float* W; u16* dst; int N, nbase;
    if (id < 4096)      { W = Wq; dst = wt_all; N = 2048; nbase = 0; }
    else if (id < 6144) { W = Wk; dst = wt_all; N = 1024; nbase = 2048; id -= 4096; }
    else if (id < 8192) { W = Wv; dst = wt_all; N = 1024; nbase = 3072; id -= 6144; }
    else                { W = Wo; dst = wo_t;  N = 2048; nbase = 0;    id -= 8192; }
    int tiles_n = N >> 5;
    int k0 = (id / tiles_n) << 5, n0 = (id % tiles_n) << 5;
    __shared__ float t[32][33];
    int tid = threadIdx.x;
    {
        int row = tid >> 3, c4 = (tid & 7) << 2;
        float4 v = *reinterpret_cast<const float4*>(&W[(size_t)(k0 + row) * N + n0 + c4]);
        t[row][c4 + 0] = v.x; t[row][c4 + 1] = v.y;
        t[row][c4 + 2] = v.z; t[row][c4 + 3] = v.w;
    }
    __syncthreads();
    {
        int n = tid >> 3, kq = (tid & 7) << 2;
        alignas(8) u16 p[4];
#pragma unroll
        for (int j = 0; j < 4; j++) p[j] = f2b(t[kq + j][n]);
        *reinterpret_cast<uint2*>(&dst[(size_t)(nbase + n0 + n) * 2048 + k0 + kq]) =
            *reinterpret_cast<uint2*>(p);
    }
}

// ---------------- concat biases bq|bk|bv -> fp32[4096] ----------------------
__global__ __launch_bounds__(256) void k_bias(const float* __restrict__ bq,
                                              const float* __restrict__ bk,
                                              const float* __restrict__ bv,
                                              float* __restrict__ dst) {
    int i = blockIdx.x * 256 + threadIdx.x;
    float v = (i < 2048) ? bq[i] : (i < 3072) ? bk[i - 2048] : bv[i - 3072];
    dst[i] = v;
}

// ---------------- bf16 MFMA GEMM: C[M][N] = A[M][K] * Bt[N][K]^T + bias -----
// 128x128 tile, BK=64 (32 MFMA per barrier pair), global_load_lds staging,
// XOR granule swizzle (8 granules/row; store pos = g ^ (row&7)) -> 2-way free.
__global__ __launch_bounds__(256) void k_gemm(
    const u16* __restrict__ A, const u16* __restrict__ Bt,
    const float* __restrict__ bias, void* __restrict__ out,
    int M, int N, int K, int out_f32) {
    __shared__ alignas(16) u16 As[128][64];
    __shared__ alignas(16) u16 Bs[128][64];
    int tid = threadIdx.x;
    int wave = tid >> 6, lane = tid & 63, quad = lane >> 4, l16 = lane & 15;
    int m0 = blockIdx.y << 7, n0 = blockIdx.x << 7;
    int wm = (wave >> 1) << 6, wn = (wave & 1) << 6;
    f4v zero = {0.f, 0.f, 0.f, 0.f};
    f4v acc[4][4];
#pragma unroll
    for (int a = 0; a < 4; a++)
#pragma unroll
        for (int b = 0; b < 4; b++) acc[a][b] = zero;
    int r0 = tid >> 3;                            // staging row 0..31
    int gsw = (tid & 7) ^ (r0 & 7);               // swizzled source granule
    const u16* gA = A + (size_t)(m0 + r0) * K + (gsw << 3);
    const u16* gB = Bt + (size_t)(n0 + r0) * K + (gsw << 3);
    for (int k0 = 0; k0 < K; k0 += 64) {
        __syncthreads();
#pragma unroll
        for (int i = 0; i < 4; i++) {
            gl_lds16(gA + (size_t)(i << 5) * K + k0, (char*)As + (i << 12) + tid * 16);
            gl_lds16(gB + (size_t)(i << 5) * K + k0, (char*)Bs + (i << 12) + tid * 16);
        }
        __syncthreads();
#pragma unroll
        for (int ks = 0; ks < 2; ks++) {
            int rg = (((ks << 2) | quad) ^ (l16 & 7)) << 3;
            s8v af[4], bf_[4];
#pragma unroll
            for (int mi = 0; mi < 4; mi++)
                af[mi] = *reinterpret_cast<const s8v*>(&As[wm + mi * 16 + l16][rg]);
#pragma unroll
            for (int ni = 0; ni < 4; ni++)
                bf_[ni] = *reinterpret_cast<const s8v*>(&Bs[wn + ni * 16 + l16][rg]);
#pragma unroll
            for (int mi = 0; mi < 4; mi++)
#pragma unroll
                for (int ni = 0; ni < 4; ni++)
                    acc[mi][ni] = MFMA16(af[mi], bf_[ni], acc[mi][ni]);
        }
    }
#pragma unroll
    for (int mi = 0; mi < 4; mi++) {
#pragma unroll
        for (int ni = 0; ni < 4; ni++) {
            int n = n0 + wn + ni * 16 + l16;
            float bsv = bias[n];
#pragma unroll
            for (int r = 0; r < 4; r++) {
                int m = m0 + wm + mi * 16 + (quad << 2) + r;
                float v = acc[mi][ni][r] + bsv;
                if (out_f32)
                    reinterpret_cast<float*>(out)[(size_t)m * N + n] = v;
                else
                    reinterpret_cast<u16*>(out)[(size_t)m * N + n] = f2b(v);
            }
        }
    }
}

// ---------------- RoPE on Q and K, reshape to [B,H,S,D] ---------------------
// Q additionally pre-scaled by scale*log2e so QK^T emerges in exp2 domain.
__global__ __launch_bounds__(256) void k_rope(const u16* __restrict__ qkv,
                                              u16* __restrict__ qr,
                                              u16* __restrict__ kr) {
    const float qscale = 0.08838834764831845f * 1.44269504088896340f;
    int row = blockIdx.x;
    int b = row >> 11, s = row & 2047;
    const u16* src = qkv + (size_t)row * 4096;
    __shared__ float lcs[64], lsn[64];
    int tid = threadIdx.x;
    if (tid < 64) {
        float fr = (float)s * exp2f((float)tid * -0.31143075889569023f);
        lcs[tid] = cosf(fr);
        lsn[tid] = sinf(fr);
    }
    __syncthreads();
    for (int u = tid; u < 1536; u += 256) {
        int hh, i;
        const u16* sp;
        u16* dp;
        float sc;
        if (u < 1024) {
            hh = u >> 6; i = u & 63;
            sp = src + hh * 128;
            dp = qr + ((size_t)(b * 16 + hh) * 2048 + s) * 128;
            sc = qscale;
        } else {
            int u2 = u - 1024;
            hh = u2 >> 6; i = u2 & 63;
            sp = src + 2048 + hh * 128;
            dp = kr + ((size_t)(b * 8 + hh) * 2048 + s) * 128;
            sc = 1.f;
        }
        float x1 = b2f(sp[i]);
        float x2 = b2f(sp[i + 64]);
        float cs = lcs[i], sn = lsn[i];
        dp[i]      = f2b((x1 * cs - x2 * sn) * sc);
        dp[i + 64] = f2b((x2 * cs + x1 * sn) * sc);
    }
}

// ---------------- V: reshape + transpose -> vt[B,HKV,D,S] bf16 --------------
__global__ __launch_bounds__(256) void k_vtrans(const u16* __restrict__ qkv,
                                                u16* __restrict__ vt) {
    int bkv = blockIdx.z, b = bkv >> 3, kv = bkv & 7;
    int s0 = blockIdx.x << 6, d0 = blockIdx.y << 5;
    __shared__ alignas(16) u16 t[32][72];
    int tid = threadIdx.x, c = tid & 31, rr = tid >> 5;
#pragma unroll
    for (int i = 0; i < 8; i++) {
        int s = s0 + rr + i * 8;
        t[c][rr + i * 8] = qkv[(size_t)(b * 2048 + s) * 4096 + 3072 + kv * 128 + d0 + c];
    }
    __syncthreads();
    int dd = tid >> 3, sc8 = (tid & 7) << 3;
    *reinterpret_cast<uint4*>(&vt[((size_t)(b * 8 + kv) * 128 + d0 + dd) * 2048 + s0 + sc8]) =
        *reinterpret_cast<const uint4*>(&t[dd][sc8]);
}

// ---------------- attention partials: one (b,h,qt128,c) unit per block ------
// Block = 4 waves; wave owns 32 q-rows (two 16-row halves). K/V frag LDS reads
// are shared by both halves (2 MFMAs per read). Fixed-reference accumulation
// (exp2 domain, pre-scaled Q); single max-reduce + rescale at unit end.
__global__ __launch_bounds__(256) void k_attn_part(const u16* __restrict__ qr,
                                                   const u16* __restrict__ kr,
                                                   const u16* __restrict__ vt,
                                                   u16* __restrict__ PVp,
                                                   float* __restrict__ scp) {
    const float NINF = -__builtin_inff();
    __shared__ alignas(16) u16 Ks[2][64 * 128];   // [key][dim], granule-swizzled
    __shared__ alignas(16) u16 Vs[2][128 * 64];   // [d][key],  granule-swizzled
    __shared__ alignas(16) u16 Pb[4][2][16][40];  // [wave][qhalf][row][32k+8pad]

    int tid = threadIdx.x;
    int wv = tid >> 6, lane = tid & 63, quad = lane >> 4, l16 = lane & 15;
    int x = blockIdx.x, h = blockIdx.y, b = blockIdx.z, kvh = h >> 1;
    int qt = qt_tab[x], c = c_tab[x], qc = qt >> 2;
    bool diag = (c == qc);
    int m3 = qt & 3;
    int nt = diag ? ((m3 + 1) << 1) : 8;          // 64-key tiles in this unit
    int kbase = c << 9;
    const u16* Qp = qr + ((size_t)(b * 16 + h) * 2048 + qt * 128 + wv * 32) * 128;
    const u16* Kp = kr + ((size_t)(b * 8 + kvh) * 2048) * 128;
    const u16* Vp = vt + ((size_t)(b * 8 + kvh) * 128) * 2048;

    s8v qf0[4], qf1[4];
#pragma unroll
    for (int sl = 0; sl < 4; sl++) {
        qf0[sl] = *reinterpret_cast<const s8v*>(&Qp[l16 * 128 + sl * 32 + (quad << 3)]);
        qf1[sl] = *reinterpret_cast<const s8v*>(&Qp[(16 + l16) * 128 + sl * 32 + (quad << 3)]);
    }
    s8v ones;
#pragma unroll
    for (int i = 0; i < 8; i++) ones[i] = (short)0x3F80;   // bf16 1.0

    int krow = tid >> 4, kg = (tid & 15) ^ krow;
    int vd = tid >> 3, vg = (tid & 7) ^ (vd & 7);
    auto stage = [&](int t) {
        int kbt = kbase + (t << 6);
        const u16* kgp = Kp + (size_t)(kbt + krow) * 128 + (kg << 3);
        const u16* vgp = Vp + (size_t)vd * 2048 + kbt + (vg << 3);
        char* kd = (char*)&Ks[t & 1][0];
        char* vdst = (char*)&Vs[t & 1][0];
#pragma unroll
        for (int i = 0; i < 4; i++) {
            gl_lds16(kgp + (size_t)(i << 4) * 128, kd + (i << 12) + tid * 16);
            gl_lds16(vgp + (size_t)(i << 5) * 2048, vdst + (i << 12) + tid * 16);
        }
    };

    f4v zero = {0.f, 0.f, 0.f, 0.f};
    f4v u0[8], u1[8], sums0 = zero, sums1 = zero;
#pragma unroll
    for (int ni = 0; ni < 8; ni++) { u0[ni] = zero; u1[ni] = zero; }
    float tmx0[4] = {NINF, NINF, NINF, NINF};
    float tmx1[4] = {NINF, NINF, NINF, NINF};
    int qg0 = wv << 1, qg1 = (wv << 1) + 1;       // 16-row q-group indices

    stage(0);
    for (int t = 0; t < nt; t++) {
        __syncthreads();             // drains stage(t) loads + WAR fence
        if (t + 1 < nt) stage(t + 1);
        const char* Kbuf = (const char*)&Ks[t & 1][0];
        const char* Vbuf = (const char*)&Vs[t & 1][0];
        // key 16-group index relative to q-tile start (full units: always active)
        int kgb = diag ? ((t << 2) - (m3 << 3)) : -1000;

#pragma unroll
        for (int s2 = 0; s2 < 2; s2++) {
            if (kgb + (s2 << 1) > qg1) continue;      // whole 32-key half masked
            bool h0act = (kgb + (s2 << 1) <= qg0);
#pragma unroll
            for (int half = 0; half < 2; half++) {
                int sub = (s2 << 1) + half;
                int kgi = kgb + sub;
                if (kgi > qg1) {                       // sub masked for both
                    if (h0act)
#pragma unroll
                        for (int r = 0; r < 4; r++)
                            Pb[wv][0][(quad << 2) + r][(half << 4) + l16] = (u16)0;
#pragma unroll
                    for (int r = 0; r < 4; r++)
                        Pb[wv][1][(quad << 2) + r][(half << 4) + l16] = (u16)0;
                    continue;
                }
                bool act0 = (kgi <= qg0);
                f4v s0 = zero, s1 = zero;
#pragma unroll
                for (int sl = 0; sl < 4; sl++) {
                    s8v kf = *reinterpret_cast<const s8v*>(
                        Kbuf + ((sub << 4) + l16) * 256 + ((((sl << 2) + quad) ^ l16) << 4));
                    if (act0) s0 = MFMA16(qf0[sl], kf, s0);
                    s1 = MFMA16(qf1[sl], kf, s1);
                }
                if (act0) {
                    bool tri = (kgi == qg0);
#pragma unroll
                    for (int r = 0; r < 4; r++) {
                        float v = s0[r];
                        if (tri && (l16 > (quad << 2) + r)) v = NINF;
                        tmx0[r] = fmaxf(tmx0[r], v);
                        Pb[wv][0][(quad << 2) + r][(half << 4) + l16] =
                            f2b(__builtin_amdgcn_exp2f(v));
                    }
                } else if (h0act) {
#pragma unroll
                    for (int r = 0; r < 4; r++)
                        Pb[wv][0][(quad << 2) + r][(half << 4) + l16] = (u16)0;
                }
                {
                    bool tri = (kgi == qg1);
#pragma unroll
                    for (int r = 0; r < 4; r++) {
                        float v = s1[r];
                        if (tri && (l16 > (quad << 2) + r)) v = NINF;
                        tmx1[r] = fmaxf(tmx1[r], v);
                        Pb[wv][1][(quad << 2) + r][(half << 4) + l16] =
                            f2b(__builtin_amdgcn_exp2f(v));
                    }
                }
            }
            // same-wave DS ordering: Pb writes visible to reads below
            s8v pf0, pf1;
            if (h0act) {
                pf0 = *reinterpret_cast<const s8v*>(&Pb[wv][0][l16][quad << 3]);
                sums0 = MFMA16(pf0, ones, sums0);
            }
            pf1 = *reinterpret_cast<const s8v*>(&Pb[wv][1][l16][quad << 3]);
            sums1 = MFMA16(pf1, ones, sums1);
#pragma unroll
            for (int ni = 0; ni < 8; ni++) {
                s8v vf = *reinterpret_cast<const s8v*>(
                    Vbuf + ((ni << 4) + l16) * 128 + ((((s2 << 2) + quad) ^ (l16 & 7)) << 4));
                if (h0act) u0[ni] = MFMA16(pf0, vf, u0[ni]);
                u1[ni] = MFMA16(pf1, vf, u1[ni]);
            }
        }
    }
    // one-time reduce + rescale, then write partials
#pragma unroll
    for (int r = 0; r < 4; r++) {
#pragma unroll
        for (int off = 1; off < 16; off <<= 1) {
            tmx0[r] = fmaxf(tmx0[r], __shfl_xor(tmx0[r], off));
            tmx1[r] = fmaxf(tmx1[r], __shfl_xor(tmx1[r], off));
        }
    }
    float resc0[4], resc1[4];
#pragma unroll
    for (int r = 0; r < 4; r++) {
        resc0[r] = __builtin_amdgcn_exp2f(-tmx0[r]);
        resc1[r] = __builtin_amdgcn_exp2f(-tmx1[r]);
    }
    int slot = (b * 16 + h) * 40 + x;
    u16* pvdst = PVp + (size_t)slot * 16384;
    int row0 = wv * 32 + (quad << 2);
#pragma unroll
    for (int ni = 0; ni < 8; ni++)
#pragma unroll
        for (int r = 0; r < 4; r++) {
            pvdst[(row0 + r) * 128 + ni * 16 + l16] = f2b(u0[ni][r] * resc0[r]);
            pvdst[(row0 + 16 + r) * 128 + ni * 16 + l16] = f2b(u1[ni][r] * resc1[r]);
        }
    if (l16 == 0) {
        float* scd = scp + (size_t)slot * 256 + row0;
#pragma unroll
        for (int r = 0; r < 4; r++) {
            scd[r] = tmx0[r] * 0.6931471805599453f;          // natural-log domain
            scd[16 + r] = tmx1[r] * 0.6931471805599453f;
            scd[128 + r] = sums0[r] * resc0[r];
            scd[144 + r] = sums1[r] * resc1[r];
        }
    }
}

// ---------------- combine partials with the exact reference scan step -------
__global__ __launch_bounds__(256) void k_attn_comb(const u16* __restrict__ PVp,
                                                   const float* __restrict__ scp,
                                                   u16* __restrict__ attnb) {
    int qt64 = blockIdx.x, h = blockIdx.y, b = blockIdx.z;
    int qt = qt64 >> 1, qc = qt >> 2;
    int tid = threadIdx.x;
    int row = ((qt64 & 1) << 6) + (tid >> 2), d0 = (tid & 3) << 5;  // row in 0..127
    int bh = b * 16 + h;
    float o[32];
#pragma unroll
    for (int i = 0; i < 32; i++) o[i] = 0.f;
    float mprev = -__builtin_inff(), dlast = 1.f;
    for (int cc = 0; cc <= qc; cc++) {
        int slot = bh * 40 + uoff40(qt, cc);
        float ch = scp[(size_t)slot * 256 + row];
        float sh = scp[(size_t)slot * 256 + 128 + row];
        float mnew = fmaxf(mprev, ch);
        float p = __expf(mprev - mnew);      // cc==0: exp(-inf)=0
        float lam = __expf(ch - mnew);
        float dd = p + lam * sh;
        float inv = 1.f / dd;
        const u16* pv = PVp + (size_t)slot * 16384 + row * 128 + d0;
#pragma unroll
        for (int k = 0; k < 4; k++) {
            s8v v8 = *reinterpret_cast<const s8v*>(pv + (k << 3));
#pragma unroll
            for (int j = 0; j < 8; j++) {
                int i = (k << 3) + j;
                o[i] = (o[i] * p + lam * b2f((u16)v8[j])) * inv;
            }
        }
        mprev = mnew;
        dlast = dd;
    }
    if (qc == 3) {   // rows >= 1536: reference's final o/d double-divides
        float inv = 1.f / dlast;
#pragma unroll
        for (int i = 0; i < 32; i++) o[i] *= inv;
    }
    alignas(16) u16 ob[32];
#pragma unroll
    for (int i = 0; i < 32; i++) ob[i] = f2b(o[i]);
    u16* dst = attnb + (size_t)(b * 2048 + qt * 128 + row) * 2048 + h * 128 + d0;
#pragma unroll
    for (int k = 0; k < 4; k++)
        reinterpret_cast<uint4*>(dst)[k] = reinterpret_cast<const uint4*>(ob)[k];
}

// ---------------------------------------------------------------------------
extern "C" void kernel_launch(void* const* d_in, const int* in_sizes, int n_in,
                              void* d_out, int out_size, void* d_ws, size_t ws_size,
                              hipStream_t stream) {
    (void)in_sizes; (void)n_in; (void)out_size; (void)ws_size;
    const float* hs = (const float*)d_in[0];
    // d_in[1] = attention_mask: causal additive, reconstructed analytically
    const float* Wq = (const float*)d_in[2];
    const float* bq = (const float*)d_in[3];
    const float* Wk = (const float*)d_in[4];
    const float* bk = (const float*)d_in[5];
    const float* Wv = (const float*)d_in[6];
    const float* bv = (const float*)d_in[7];
    const float* Wo = (const float*)d_in[8];
    const float* bo = (const float*)d_in[9];

    char* ws = (char*)d_ws;
    u16* hsb      = (u16*)(ws);                              // 16 MiB
    u16* qr       = hsb;                                     // alias after GEMM1
    u16* attnb    = hsb;                                     // alias after partials
    u16* wt_all   = (u16*)(ws + (16u << 20));                // 16 MiB
    u16* kr       = wt_all;                                  // alias after GEMM1
    u16* vt       = (u16*)(ws + (24u << 20));                // 8 MiB
    u16* wo_t     = (u16*)(ws + (32u << 20));                // 8 MiB
    float* bias_c = (float*)(ws + (40u << 20));              // 64 KiB
    u16* qkv      = (u16*)(ws + (40u << 20) + 65536);        // 32 MiB
    u16* PVp      = qkv;                                     // alias, 40 MiB
    float* scp    = (float*)(ws + (40u << 20) + 65536 + 41943040u);  // 1.25 MiB

    k_cast_hs<<<8192, 256, 0, stream>>>(hs, hsb);
    k_transpose_w<<<12288, 256, 0, stream>>>(Wq, Wk, Wv, Wo, wt_all, wo_t);
    k_bias<<<16, 256, 0, stream>>>(bq, bk, bv, bias_c);
    k_gemm<<<dim3(32, 32), 256, 0, stream>>>(hsb, wt_all, bias_c, qkv,
                                             4096, 4096, 2048, 0);
    k_rope<<<4096, 256, 0, stream>>>(qkv, qr, kr);
    k_vtrans<<<dim3(32, 4, 16), 256, 0, stream>>>(qkv, vt);
    k_attn_part<<<dim3(40, 16, 2), 256, 0, stream>>>(qr, kr, vt, PVp, scp);
    k_attn_comb<<<dim3(32, 16, 2), 256, 0, stream>>>(PVp, scp, attnb);
    k_gemm<<<dim3(16, 32), 256, 0, stream>>>(attnb, wo_t, bo, d_out,
                                             4096, 2048, 2048, 1);
}